// Round 2
// baseline (281.215 us; speedup 1.0000x reference)
//
#include <hip/hip_runtime.h>

#define NB    16384
#define SS    300
#define AA    30
#define EMB_  256
#define MTOK  8
#define MPROT 16
#define HENC  256
#define HDEC  128
#define NMF   12
#define RROWS 16
#define SCALE 0.0625f   // 256^-0.5
#define ETA0  0.1f

// ---------------------------------------------------------------------------
// Pre-kernel: batch-independent precompute.
// blocks 0..127: W3[i, c] = sum_e enc_W2[i, m*256+e] * proto[n, e], c = m*16+n
//                cmn[c]   = sum_e enc_b2[m*256+e]   * proto[n, e]
// block 128:     conc[m, a] (16x30) via decoder MLP
// ---------------------------------------------------------------------------
__global__ __launch_bounds__(256) void pre_kernel(
    const float* __restrict__ proto, const float* __restrict__ W2,
    const float* __restrict__ b2,
    const float* __restrict__ dW1, const float* __restrict__ db1,
    const float* __restrict__ dW2, const float* __restrict__ db2,
    float* __restrict__ W3, float* __restrict__ cmn, float* __restrict__ conc)
{
    const int t = threadIdx.x;
    if (blockIdx.x < 128) {
        const int c = blockIdx.x;
        const int m = c >> 4, n = c & 15;
        __shared__ float pr[EMB_];
        pr[t] = proto[n * EMB_ + t];
        __syncthreads();
        const float* w2row = W2 + (size_t)t * 2048 + m * EMB_;
        float acc = 0.f;
        #pragma unroll 8
        for (int e = 0; e < EMB_; ++e) acc += w2row[e] * pr[e];
        W3[t * 128 + c] = acc;
        if (t == 0) {
            float ca = 0.f;
            for (int e = 0; e < EMB_; ++e) ca += b2[m * EMB_ + e] * pr[e];
            cmn[c] = ca;
        }
    } else {
        __shared__ float hd[MPROT][HDEC];
        for (int idx = t; idx < MPROT * HDEC; idx += 256) {
            const int m = idx >> 7, hh = idx & 127;
            float acc = db1[m * HDEC + hh];
            const float* w = dW1 + (size_t)m * EMB_ * HDEC + hh;
            const float* p = proto + m * EMB_;
            for (int e = 0; e < EMB_; ++e) acc += p[e] * w[e * HDEC];
            hd[m][hh] = fmaxf(acc, 0.f);
        }
        __syncthreads();
        for (int idx = t; idx < MPROT * AA; idx += 256) {
            const int m = idx / AA, a = idx % AA;
            float acc = db2[m * AA + a];
            const float* w = dW2 + (size_t)m * HDEC * AA + a;
            for (int h = 0; h < HDEC; ++h) acc += hd[m][h] * w[h * AA];
            // softplus, stable
            conc[idx] = fmaxf(acc, 0.f) + log1pf(expf(-fabsf(acc)));
        }
    }
}

// ---------------------------------------------------------------------------
// Main kernel: 16 rows per block, 256 threads.
// ---------------------------------------------------------------------------
__global__ __launch_bounds__(256, 2) void main_kernel(
    const float* __restrict__ state, const float* __restrict__ fitness,
    const float* __restrict__ proto,
    const float* __restrict__ W1, const float* __restrict__ b1,
    const float* __restrict__ ln_g, const float* __restrict__ ln_b,
    const float* __restrict__ tcW, const float* __restrict__ tcb,
    const float* __restrict__ cW,  const float* __restrict__ cb,
    const float* __restrict__ pw,
    const float* __restrict__ W3, const float* __restrict__ cmn,
    const float* __restrict__ conc,
    float* __restrict__ out)
{
    const int t = threadIdx.x;
    const int row0 = blockIdx.x * RROWS;
    const int wid = t >> 6, lane = t & 63;

    __shared__ float s_state[RROWS][304];     // padded to 304 (16B-aligned rows)
    __shared__ float s_dang[RROWS][256];
    __shared__ float s_h[RROWS][256];
    __shared__ float s_log[RROWS][128];
    __shared__ float s_mf[RROWS][NMF];
    __shared__ float s_crisis[RROWS];
    __shared__ float s_ddot[RROWS][16];       // danger.proto; later reused as w_ot
    __shared__ float s_wrep[RROWS][16];
    __shared__ float s_w[RROWS][16];
    __shared__ float s_mu[RROWS], s_rstd[RROWS];
    __shared__ float s_mix[RROWS][AA];
    __shared__ float s_inv[RROWS];

    // ---- load state tile (16 x 300) ----
    for (int idx = t; idx < RROWS * SS; idx += 256) {
        const int r = idx / SS, i = idx - r * SS;
        s_state[r][i] = state[(size_t)(row0 + r) * SS + i];
    }
    __syncthreads();

    // ---- market features (12 per row) ----
    if (t < RROWS) {
        const int r = t;
        const float bal = s_state[r][0];
        float pm = 0.f;
        for (int i = 0; i < 30; ++i) pm += s_state[r][1 + i];
        pm *= (1.f / 30.f);
        float vs = 0.f;
        for (int i = 0; i < 30; ++i) { const float d = s_state[r][1 + i] - pm; vs += d * d; }
        const float pstd = sqrtf(vs / 29.f) + 1e-8f;
        float tv = bal;
        for (int i = 0; i < 30; ++i) tv += s_state[r][1 + i] * s_state[r][31 + i];
        const float cr = bal / (tv + 1e-8f);
        s_mf[r][0] = bal; s_mf[r][1] = pm; s_mf[r][2] = pstd; s_mf[r][3] = cr;
        for (int k = 0; k < 8; ++k) s_mf[r][4 + k] = s_state[r][61 + 30 * k];
    }
    __syncthreads();

    // ---- danger = tanh(mf @ tc_W + tc_b), col t ----
    {
        float wreg[NMF];
        #pragma unroll
        for (int k = 0; k < NMF; ++k) wreg[k] = tcW[k * 256 + t];
        const float tb = tcb[t];
        #pragma unroll
        for (int r = 0; r < RROWS; ++r) {
            float acc = tb;
            #pragma unroll
            for (int k = 0; k < NMF; ++k) acc = fmaf(s_mf[r][k], wreg[k], acc);
            s_dang[r][t] = tanhf(acc);
        }
    }
    __syncthreads();

    // ---- crisis (wave reductions, 4 rows per wave) ----
    {
        float cw4[4];
        #pragma unroll
        for (int u = 0; u < 4; ++u) cw4[u] = cW[lane + 64 * u];
        const float cbv = cb[0];
        for (int rr = 0; rr < 4; ++rr) {
            const int r = wid * 4 + rr;
            float p = 0.f;
            #pragma unroll
            for (int u = 0; u < 4; ++u) p += s_dang[r][lane + 64 * u] * cw4[u];
            for (int off = 32; off; off >>= 1) p += __shfl_down(p, off);
            if (lane == 0) s_crisis[r] = 1.f / (1.f + expf(-(p + cbv)));
        }
    }

    // ---- ddot[r][n] = danger[r] . proto[n] ----
    {
        const int r = t >> 4, n = t & 15;
        const float* pn = proto + n * EMB_;
        float acc = 0.f;
        for (int j = 0; j < 256; ++j) acc += s_dang[r][j] * pn[j];
        s_ddot[r][n] = acc;
    }

    // ---- GEMM1: h_pre[r][t] = state[r] @ W1[:, t] + b1[t] ----
    {
        float facc[RROWS];
        const float bj = b1[t];
        #pragma unroll
        for (int r = 0; r < RROWS; ++r) facc[r] = bj;
        const float* w1col = W1 + t;
        for (int ic = 0; ic < SS / 4; ++ic) {
            const int i = ic * 4;
            const float w0 = w1col[(i + 0) * 256];
            const float w1v = w1col[(i + 1) * 256];
            const float w2v = w1col[(i + 2) * 256];
            const float w3v = w1col[(i + 3) * 256];
            #pragma unroll
            for (int r = 0; r < RROWS; ++r) {
                const float4 sv = *(const float4*)&s_state[r][i];
                float a = facc[r];
                a = fmaf(sv.x, w0, a);
                a = fmaf(sv.y, w1v, a);
                a = fmaf(sv.z, w2v, a);
                a = fmaf(sv.w, w3v, a);
                facc[r] = a;
            }
        }
        #pragma unroll
        for (int r = 0; r < RROWS; ++r) s_h[r][t] = facc[r];
    }
    __syncthreads();

    // ---- LayerNorm stats (4 rows per wave) ----
    for (int rr = 0; rr < 4; ++rr) {
        const int r = wid + rr * 4;
        float s = 0.f, s2 = 0.f;
        #pragma unroll
        for (int u = 0; u < 4; ++u) {
            const float v = s_h[r][lane + 64 * u];
            s += v; s2 += v * v;
        }
        for (int off = 32; off; off >>= 1) { s += __shfl_down(s, off); s2 += __shfl_down(s2, off); }
        if (lane == 0) {
            const float mu = s * (1.f / 256.f);
            const float var = s2 * (1.f / 256.f) - mu * mu;
            s_mu[r] = mu; s_rstd[r] = rsqrtf(var + 1e-5f);
        }
    }
    __syncthreads();

    // ---- apply LN + relu ----
    {
        const float gj = ln_g[t], bj = ln_b[t];
        #pragma unroll
        for (int r = 0; r < RROWS; ++r) {
            const float v = (s_h[r][t] - s_mu[r]) * s_rstd[r] * gj + bj;
            s_h[r][t] = fmaxf(v, 0.f);
        }
    }
    __syncthreads();

    // ---- GEMM2': logits[r][c] = SCALE*(h[r]@W3[:,c] + cmn[c] + ddot[r][n]) ----
    {
        const int c = t & 127, q = t >> 7;   // q selects rows 8q..8q+7
        float acc2[8];
        #pragma unroll
        for (int rr = 0; rr < 8; ++rr) acc2[rr] = 0.f;
        const float* w3p = W3 + c;
        for (int jc = 0; jc < 64; ++jc) {
            const int j = jc * 4;
            const float w0 = w3p[(j + 0) * 128];
            const float w1v = w3p[(j + 1) * 128];
            const float w2v = w3p[(j + 2) * 128];
            const float w3v = w3p[(j + 3) * 128];
            #pragma unroll
            for (int rr = 0; rr < 8; ++rr) {
                const float4 hv = *(const float4*)&s_h[q * 8 + rr][j];
                float a = acc2[rr];
                a = fmaf(hv.x, w0, a);
                a = fmaf(hv.y, w1v, a);
                a = fmaf(hv.z, w2v, a);
                a = fmaf(hv.w, w3v, a);
                acc2[rr] = a;
            }
        }
        const int n = c & 15;
        const float cc = cmn[c];
        #pragma unroll
        for (int rr = 0; rr < 8; ++rr) {
            const int r = q * 8 + rr;
            s_log[r][c] = SCALE * (acc2[rr] + cc + s_ddot[r][n]);
        }
    }
    __syncthreads();

    // ---- softmax over n (16) per (r, m): 128 pairs ----
    if (t < 128) {
        const int r = t >> 3, m = t & 7;
        float* lg = &s_log[r][m * 16];
        float mx = lg[0];
        for (int n = 1; n < 16; ++n) mx = fmaxf(mx, lg[n]);
        float sum = 0.f;
        float p[16];
        for (int n = 0; n < 16; ++n) { p[n] = expf(lg[n] - mx); sum += p[n]; }
        const float inv = 1.f / sum;
        for (int n = 0; n < 16; ++n) lg[n] = p[n] * inv;
    }
    __syncthreads();

    // ---- w_ot (reuse s_ddot) and unnormalized w_rep ----
    {
        const int r = t >> 4, n = t & 15;
        float wot = 0.f;
        #pragma unroll
        for (int m = 0; m < 8; ++m) wot += s_log[r][m * 16 + n];
        s_ddot[r][n] = wot * (1.f / 8.f);
        const float fit = fitness[(size_t)(row0 + r) * 16 + n];
        s_wrep[r][n] = pw[n] * expf(ETA0 * fit);
    }
    __syncthreads();

    // ---- blend weights per row ----
    if (t < RROWS) {
        const int r = t;
        float srep = 0.f;
        for (int n = 0; n < 16; ++n) srep += s_wrep[r][n];
        const float irep = 1.f / (srep + 1e-8f);
        const float alpha = 0.06f + 0.24f * (1.f - s_crisis[r]);
        float wn[16]; float sw = 0.f;
        for (int n = 0; n < 16; ++n) {
            wn[n] = alpha * s_ddot[r][n] + (1.f - alpha) * s_wrep[r][n] * irep;
            sw += wn[n];
        }
        const float isw = 1.f / (sw + 1e-8f);
        for (int n = 0; n < 16; ++n) s_w[r][n] = wn[n] * isw;
    }
    __syncthreads();

    // ---- mixed = w @ conc + 1 ----
    for (int idx = t; idx < RROWS * AA; idx += 256) {
        const int r = idx / AA, a = idx % AA;
        float acc = 1.f;
        for (int n = 0; n < 16; ++n) acc = fmaf(s_w[r][n], conc[n * AA + a], acc);
        s_mix[r][a] = acc;
    }
    __syncthreads();

    // ---- softmax over 30 actions ----
    if (t < RROWS) {
        const int r = t;
        float mx = s_mix[r][0];
        for (int a = 1; a < AA; ++a) mx = fmaxf(mx, s_mix[r][a]);
        float sum = 0.f;
        for (int a = 0; a < AA; ++a) { const float p = expf(s_mix[r][a] - mx); s_mix[r][a] = p; sum += p; }
        s_inv[r] = 1.f / sum;
    }
    __syncthreads();

    // ---- write output ----
    for (int idx = t; idx < RROWS * AA; idx += 256) {
        const int r = idx / AA, a = idx % AA;
        out[(size_t)(row0 + r) * AA + a] = s_mix[r][a] * s_inv[r];
    }
}

extern "C" void kernel_launch(void* const* d_in, const int* in_sizes, int n_in,
                              void* d_out, int out_size, void* d_ws, size_t ws_size,
                              hipStream_t stream) {
    const float* state   = (const float*)d_in[0];
    const float* fitness = (const float*)d_in[1];
    const float* proto   = (const float*)d_in[2];
    const float* enc_W1  = (const float*)d_in[3];
    const float* enc_b1  = (const float*)d_in[4];
    const float* ln_g    = (const float*)d_in[5];
    const float* ln_b    = (const float*)d_in[6];
    const float* enc_W2  = (const float*)d_in[7];
    const float* enc_b2  = (const float*)d_in[8];
    const float* dec_W1  = (const float*)d_in[9];
    const float* dec_b1  = (const float*)d_in[10];
    const float* dec_W2  = (const float*)d_in[11];
    const float* dec_b2  = (const float*)d_in[12];
    const float* tc_W    = (const float*)d_in[13];
    const float* tc_b    = (const float*)d_in[14];
    const float* tc_cW   = (const float*)d_in[15];
    const float* tc_cb   = (const float*)d_in[16];
    // d_in[17], d_in[18]: tc_zW / tc_zb — z is never used by the output
    const float* w_prev  = (const float*)d_in[19];
    float* out = (float*)d_out;

    float* W3   = (float*)d_ws;                 // 256*128
    float* cmn  = W3 + 256 * 128;               // 128
    float* conc = cmn + 128;                    // 16*30

    pre_kernel<<<129, 256, 0, stream>>>(proto, enc_W2, enc_b2,
                                        dec_W1, dec_b1, dec_W2, dec_b2,
                                        W3, cmn, conc);
    main_kernel<<<NB / RROWS, 256, 0, stream>>>(state, fitness, proto,
                                                enc_W1, enc_b1, ln_g, ln_b,
                                                tc_W, tc_b, tc_cW, tc_cb, w_prev,
                                                W3, cmn, conc, out);
}

// Round 3
// 155.013 us; speedup vs baseline: 1.8141x; 1.8141x over previous
//
#include <hip/hip_runtime.h>

typedef __attribute__((ext_vector_type(8))) short bf16x8;
typedef __attribute__((ext_vector_type(4))) float f32x4;

#define NBATCH 16384
#define SS     300
#define AA     30
#define ROWS   32      // rows per block
#define SSTR   352     // bf16 stride, state LDS (176 dw, %32=16 -> 2-way = free)
#define HSTR   280     // bf16 stride, h/danger LDS (140 dw, 4-row step %32=16 -> 2-way)
#define LSTR   132     // fp32 stride, logits LDS
#define K1P    320     // K of GEMM1 padded (10 k-tiles)
#define SCALEF 0.0625f // 256^-0.5
#define ETA0   0.1f

__device__ __forceinline__ short f2b(float x) {
    unsigned u = __float_as_uint(x);
    unsigned r = (u + 0x7FFFu + ((u >> 16) & 1u)) >> 16;
    return (short)r;
}
__device__ __forceinline__ float b2f(short s) {
    return __uint_as_float(((unsigned)(unsigned short)s) << 16);
}
__device__ __forceinline__ float tanh_fast(float x) {
    float e = __expf(2.f * x);
    return 1.f - 2.f / (e + 1.f);
}

// ---------------------------------------------------------------------------
// Pre-kernel (grid = 161 blocks):
//  blocks 0..127  : W3T[c][j] = sum_e W2[j][m*256+e]*proto[n][e]  (bf16), c=m*16+n
//                   thread 0 also cmn[c] = sum_e b2[m*256+e]*proto[n][e]
//  blocks 128..143: decoder conc[m][a] (fp32), one m per block
//  blocks 144..159: W1T[n][k] bf16 (k padded 300->320 with zeros)
//  block  160     : protoB bf16 copy
// ---------------------------------------------------------------------------
__global__ __launch_bounds__(256) void pre_kernel(
    const float* __restrict__ proto, const float* __restrict__ W2,
    const float* __restrict__ b2,   const float* __restrict__ W1,
    const float* __restrict__ dW1,  const float* __restrict__ db1,
    const float* __restrict__ dW2,  const float* __restrict__ db2,
    short* __restrict__ W1T, short* __restrict__ W3T, short* __restrict__ protoB,
    float* __restrict__ cmn, float* __restrict__ conc)
{
    const int t = threadIdx.x;
    const int bid = blockIdx.x;
    if (bid < 128) {
        const int c = bid, m = c >> 4, n = c & 15;
        __shared__ float pr[256];
        pr[t] = proto[n * 256 + t];
        __syncthreads();
        const float* w2 = W2 + (size_t)t * 2048 + m * 256;
        float acc = 0.f;
        #pragma unroll 8
        for (int e = 0; e < 256; ++e) acc += w2[e] * pr[e];
        W3T[c * 256 + t] = f2b(acc);
        if (t == 0) {
            float ca = 0.f;
            for (int e = 0; e < 256; ++e) ca += b2[m * 256 + e] * pr[e];
            cmn[c] = ca;
        }
    } else if (bid < 144) {
        const int m = bid - 128;
        __shared__ float hd[128];
        if (t < 128) {
            float acc = db1[m * 128 + t];
            const float* w = dW1 + (size_t)m * 256 * 128 + t;
            const float* p = proto + m * 256;
            for (int e = 0; e < 256; ++e) acc += p[e] * w[e * 128];
            hd[t] = fmaxf(acc, 0.f);
        }
        __syncthreads();
        if (t < AA) {
            float acc = db2[m * AA + t];
            const float* w = dW2 + (size_t)m * 128 * AA + t;
            for (int h = 0; h < 128; ++h) acc += hd[h] * w[h * AA];
            conc[m * AA + t] = fmaxf(acc, 0.f) + log1pf(__expf(-fabsf(acc)));
        }
    } else if (bid < 160) {
        const int bn = bid - 144;
        const int nl = t >> 4, kl = t & 15;
        const int n = bn * 16 + nl;
        for (int it = 0; it < 20; ++it) {
            const int k = kl + it * 16;
            const float v = (k < SS) ? W1[(size_t)k * 256 + n] : 0.f;
            W1T[n * K1P + k] = f2b(v);
        }
    } else {
        for (int i = t; i < 16 * 256; i += 256) protoB[i] = f2b(proto[i]);
    }
}

// ---------------------------------------------------------------------------
// Main kernel: 32 rows/block, 512 blocks, 256 threads (4 waves).
// ---------------------------------------------------------------------------
__global__ __launch_bounds__(256, 3) void main_kernel(
    const float* __restrict__ state, const float* __restrict__ fitness,
    const float* __restrict__ b1,
    const float* __restrict__ ln_g, const float* __restrict__ ln_b,
    const float* __restrict__ tcW,  const float* __restrict__ tcb,
    const float* __restrict__ cW,   const float* __restrict__ cb,
    const float* __restrict__ pw,
    const short* __restrict__ W1T,  const short* __restrict__ W3T,
    const short* __restrict__ protoB,
    const float* __restrict__ cmn,  const float* __restrict__ conc,
    float* __restrict__ out)
{
    const int t    = threadIdx.x;
    const int row0 = blockIdx.x * ROWS;
    const int w    = t >> 6;          // wave id 0..3
    const int lane = t & 63;
    const int l15  = lane & 15;
    const int q    = lane >> 4;       // quad id 0..3

    __shared__ short sA[ROWS * SSTR];     // state bf16 -> h bf16 (stride HSTR); tail: wrep
    __shared__ short sB[ROWS * HSTR];     // danger bf16 -> logits fp32
    __shared__ float s_mf[ROWS][12];
    __shared__ float s_red[ROWS][8];
    __shared__ float s_mu[ROWS], s_rstd[ROWS];
    __shared__ float s_ddot[ROWS * 16];   // danger.proto -> w_ot -> w
    __shared__ float s_crisis[ROWS];
    __shared__ float s_cmn[128];
    __shared__ float s_conc[16 * AA];

    float* s_log  = (float*)sB;                 // [ROWS][LSTR]
    float* s_wrep = (float*)&sA[ROWS * HSTR];   // 32*16 fp32, past h region (8960)

    // ---- phase 1: stage state (bf16, zero-padded K) + small tables ----
    for (int idx = t; idx < ROWS * K1P; idx += 256) {
        const int r = idx / K1P, k = idx - r * K1P;
        sA[r * SSTR + k] = (k < SS) ? f2b(state[(size_t)(row0 + r) * SS + k]) : (short)0;
    }
    for (int idx = t; idx < 128 + 16 * AA; idx += 256) {
        if (idx < 128) s_cmn[idx] = cmn[idx];
        else s_conc[idx - 128] = conc[idx - 128];
    }
    __syncthreads();

    // ---- phase 2: market features, 8 lanes per row ----
    {
        const int r = t >> 3, g = t & 7;
        float sp = 0.f, sp2 = 0.f, sps = 0.f;
        const int i0 = g * 4, i1 = (g == 7) ? 2 : 4;
        for (int i = 0; i < i1; ++i) {
            const float p = b2f(sA[r * SSTR + 1 + i0 + i]);
            const float s = b2f(sA[r * SSTR + 31 + i0 + i]);
            sp += p; sp2 += p * p; sps += p * s;
        }
        for (int off = 1; off < 8; off <<= 1) {
            sp  += __shfl_xor(sp, off);
            sp2 += __shfl_xor(sp2, off);
            sps += __shfl_xor(sps, off);
        }
        s_mf[r][4 + g] = b2f(sA[r * SSTR + 61 + 30 * g]);   // tech
        if (g == 0) {
            const float bal = b2f(sA[r * SSTR + 0]);
            const float pm = sp * (1.f / 30.f);
            const float var = (sp2 - 30.f * pm * pm) * (1.f / 29.f);
            const float pstd = sqrtf(fmaxf(var, 0.f)) + 1e-8f;
            const float tv = bal + sps;
            s_mf[r][0] = bal; s_mf[r][1] = pm; s_mf[r][2] = pstd;
            s_mf[r][3] = bal / (tv + 1e-8f);
        }
    }
    __syncthreads();

    // ---- phase 3: danger[r][t] = tanh(mf @ tcW + tcb), col t, all 32 rows ----
    {
        float wreg[12];
        #pragma unroll
        for (int k = 0; k < 12; ++k) wreg[k] = tcW[k * 256 + t];
        const float tb = tcb[t];
        for (int r = 0; r < ROWS; ++r) {
            float acc = tb;
            #pragma unroll
            for (int k = 0; k < 12; ++k) acc = fmaf(s_mf[r][k], wreg[k], acc);
            sB[r * HSTR + t] = f2b(tanh_fast(acc));
        }
    }
    __syncthreads();

    // ---- phase 4: waves 0,1 -> ddot MFMA; waves 2,3 -> crisis ----
    if (w < 2) {
        f32x4 accd = {0.f, 0.f, 0.f, 0.f};
        const int mt = w;
        for (int kt = 0; kt < 8; ++kt) {
            bf16x8 a = *(const bf16x8*)&sB[(mt * 16 + l15) * HSTR + kt * 32 + q * 8];
            bf16x8 b = *(const bf16x8*)&protoB[l15 * 256 + kt * 32 + q * 8];
            accd = __builtin_amdgcn_mfma_f32_16x16x32_bf16(a, b, accd, 0, 0, 0);
        }
        #pragma unroll
        for (int reg = 0; reg < 4; ++reg) {
            const int row = mt * 16 + q * 4 + reg;
            s_ddot[row * 16 + l15] = accd[reg];
        }
    } else {
        const float4 cw = *(const float4*)&cW[lane * 4];
        const float cbv = cb[0];
        for (int rr = 0; rr < 16; ++rr) {
            const int row = (w - 2) * 16 + rr;
            const short* dp = &sB[row * HSTR + lane * 4];
            float p = b2f(dp[0]) * cw.x + b2f(dp[1]) * cw.y
                    + b2f(dp[2]) * cw.z + b2f(dp[3]) * cw.w;
            for (int off = 32; off; off >>= 1) p += __shfl_down(p, off);
            if (lane == 0) s_crisis[row] = 1.f / (1.f + __expf(-(p + cbv)));
        }
    }

    // ---- phase 5: GEMM1 MFMA: h_pre = state @ W1 ----
    f32x4 acc[2][4];
    #pragma unroll
    for (int mt = 0; mt < 2; ++mt)
        #pragma unroll
        for (int u = 0; u < 4; ++u) acc[mt][u] = (f32x4){0.f, 0.f, 0.f, 0.f};
    for (int kt = 0; kt < 10; ++kt) {
        bf16x8 a0 = *(const bf16x8*)&sA[l15 * SSTR + kt * 32 + q * 8];
        bf16x8 a1 = *(const bf16x8*)&sA[(l15 + 16) * SSTR + kt * 32 + q * 8];
        bf16x8 bfr[4];
        #pragma unroll
        for (int u = 0; u < 4; ++u)
            bfr[u] = *(const bf16x8*)&W1T[(w * 64 + u * 16 + l15) * K1P + kt * 32 + q * 8];
        #pragma unroll
        for (int u = 0; u < 4; ++u) {
            acc[0][u] = __builtin_amdgcn_mfma_f32_16x16x32_bf16(a0, bfr[u], acc[0][u], 0, 0, 0);
            acc[1][u] = __builtin_amdgcn_mfma_f32_16x16x32_bf16(a1, bfr[u], acc[1][u], 0, 0, 0);
        }
    }

    // ---- phase 6: + b1, LN partial sums from D-regs (quad shuffle reduce) ----
    {
        float b1v[4];
        #pragma unroll
        for (int u = 0; u < 4; ++u) b1v[u] = b1[w * 64 + u * 16 + l15];
        #pragma unroll
        for (int mt = 0; mt < 2; ++mt) {
            #pragma unroll
            for (int reg = 0; reg < 4; ++reg) {
                float s = 0.f, s2 = 0.f;
                #pragma unroll
                for (int u = 0; u < 4; ++u) {
                    const float v = acc[mt][u][reg] + b1v[u];
                    acc[mt][u][reg] = v;
                    s += v; s2 += v * v;
                }
                for (int off = 1; off < 16; off <<= 1) {
                    s  += __shfl_xor(s, off);
                    s2 += __shfl_xor(s2, off);
                }
                if (l15 == 0) {
                    const int row = mt * 16 + q * 4 + reg;
                    s_red[row][w * 2]     = s;
                    s_red[row][w * 2 + 1] = s2;
                }
            }
        }
    }
    __syncthreads();
    if (t < ROWS) {
        float S = 0.f, S2 = 0.f;
        #pragma unroll
        for (int ww = 0; ww < 4; ++ww) { S += s_red[t][2 * ww]; S2 += s_red[t][2 * ww + 1]; }
        const float mu = S * (1.f / 256.f);
        const float var = S2 * (1.f / 256.f) - mu * mu;
        s_mu[t] = mu; s_rstd[t] = rsqrtf(var + 1e-5f);
    }
    __syncthreads();

    // ---- phase 7: LN apply + relu + bf16 -> sA (stride HSTR) ----
    {
        float gv[4], bv[4];
        #pragma unroll
        for (int u = 0; u < 4; ++u) {
            gv[u] = ln_g[w * 64 + u * 16 + l15];
            bv[u] = ln_b[w * 64 + u * 16 + l15];
        }
        #pragma unroll
        for (int mt = 0; mt < 2; ++mt)
            #pragma unroll
            for (int reg = 0; reg < 4; ++reg) {
                const int row = mt * 16 + q * 4 + reg;
                const float mu = s_mu[row], rs = s_rstd[row];
                #pragma unroll
                for (int u = 0; u < 4; ++u) {
                    const int col = w * 64 + u * 16 + l15;
                    const float v = fmaxf((acc[mt][u][reg] - mu) * rs * gv[u] + bv[u], 0.f);
                    sA[row * HSTR + col] = f2b(v);
                }
            }
    }
    __syncthreads();

    // ---- phase 8: GEMM2' MFMA: logits = SCALE*(h @ W3T + cmn + ddot) ----
    {
        f32x4 acc2[2][2];
        #pragma unroll
        for (int mt = 0; mt < 2; ++mt)
            #pragma unroll
            for (int ct = 0; ct < 2; ++ct) acc2[mt][ct] = (f32x4){0.f, 0.f, 0.f, 0.f};
        for (int kt = 0; kt < 8; ++kt) {
            bf16x8 a0 = *(const bf16x8*)&sA[l15 * HSTR + kt * 32 + q * 8];
            bf16x8 a1 = *(const bf16x8*)&sA[(l15 + 16) * HSTR + kt * 32 + q * 8];
            bf16x8 b0 = *(const bf16x8*)&W3T[(w * 32 + l15) * 256 + kt * 32 + q * 8];
            bf16x8 b1f = *(const bf16x8*)&W3T[(w * 32 + 16 + l15) * 256 + kt * 32 + q * 8];
            acc2[0][0] = __builtin_amdgcn_mfma_f32_16x16x32_bf16(a0, b0, acc2[0][0], 0, 0, 0);
            acc2[0][1] = __builtin_amdgcn_mfma_f32_16x16x32_bf16(a0, b1f, acc2[0][1], 0, 0, 0);
            acc2[1][0] = __builtin_amdgcn_mfma_f32_16x16x32_bf16(a1, b0, acc2[1][0], 0, 0, 0);
            acc2[1][1] = __builtin_amdgcn_mfma_f32_16x16x32_bf16(a1, b1f, acc2[1][1], 0, 0, 0);
        }
        const float cm0 = s_cmn[w * 32 + l15], cm1 = s_cmn[w * 32 + 16 + l15];
        #pragma unroll
        for (int mt = 0; mt < 2; ++mt)
            #pragma unroll
            for (int reg = 0; reg < 4; ++reg) {
                const int row = mt * 16 + q * 4 + reg;
                const float dd = s_ddot[row * 16 + l15];
                s_log[row * LSTR + w * 32 + l15]      = SCALEF * (acc2[mt][0][reg] + cm0 + dd);
                s_log[row * LSTR + w * 32 + 16 + l15] = SCALEF * (acc2[mt][1][reg] + cm1 + dd);
            }
    }
    __syncthreads();

    // ---- phase 9: softmax over n (16) per (r,m) ----
    {
        const int r = t >> 3, m = t & 7;
        float* lg = &s_log[r * LSTR + m * 16];
        float mx = lg[0];
        #pragma unroll
        for (int n = 1; n < 16; ++n) mx = fmaxf(mx, lg[n]);
        float sum = 0.f, p[16];
        #pragma unroll
        for (int n = 0; n < 16; ++n) { p[n] = __expf(lg[n] - mx); sum += p[n]; }
        const float inv = 1.f / sum;
        #pragma unroll
        for (int n = 0; n < 16; ++n) lg[n] = p[n] * inv;
    }
    __syncthreads();

    // ---- phase 10: w_ot (overwrite s_ddot) + unnormalized w_rep ----
    for (int it = 0; it < 2; ++it) {
        const int idx = t + it * 256;
        const int r = idx >> 4, n = idx & 15;
        float wot = 0.f;
        #pragma unroll
        for (int m = 0; m < 8; ++m) wot += s_log[r * LSTR + m * 16 + n];
        s_ddot[idx] = wot * 0.125f;
        s_wrep[idx] = pw[n] * __expf(ETA0 * fitness[(size_t)(row0 + r) * 16 + n]);
    }
    __syncthreads();

    // ---- phase 11: blend -> w (in place in s_ddot) ----
    if (t < ROWS) {
        float srep = 0.f;
        #pragma unroll
        for (int n = 0; n < 16; ++n) srep += s_wrep[t * 16 + n];
        const float irep = 1.f / (srep + 1e-8f);
        const float alpha = 0.06f + 0.24f * (1.f - s_crisis[t]);
        float wn[16], sw = 0.f;
        #pragma unroll
        for (int n = 0; n < 16; ++n) {
            wn[n] = alpha * s_ddot[t * 16 + n] + (1.f - alpha) * s_wrep[t * 16 + n] * irep;
            sw += wn[n];
        }
        const float isw = 1.f / (sw + 1e-8f);
        #pragma unroll
        for (int n = 0; n < 16; ++n) s_ddot[t * 16 + n] = wn[n] * isw;
    }
    __syncthreads();

    // ---- phase 12: mixed = w@conc + 1, softmax over 30, write out ----
    {
        const int r = w * 8 + (lane >> 3);
        const int a0 = lane & 7;
        float wreg[16];
        #pragma unroll
        for (int n = 0; n < 16; ++n) wreg[n] = s_ddot[r * 16 + n];
        float mix[4];
        #pragma unroll
        for (int j = 0; j < 4; ++j) {
            const int a = a0 + 8 * j;
            if (a < AA) {
                float m = 1.f;
                #pragma unroll
                for (int n = 0; n < 16; ++n) m = fmaf(wreg[n], s_conc[n * AA + a], m);
                mix[j] = m;
            } else mix[j] = -1e30f;
        }
        float mx = fmaxf(fmaxf(mix[0], mix[1]), fmaxf(mix[2], mix[3]));
        for (int off = 1; off < 8; off <<= 1) mx = fmaxf(mx, __shfl_xor(mx, off));
        float se = 0.f;
        #pragma unroll
        for (int j = 0; j < 4; ++j) {
            if (a0 + 8 * j < AA) { mix[j] = __expf(mix[j] - mx); se += mix[j]; }
        }
        for (int off = 1; off < 8; off <<= 1) se += __shfl_xor(se, off);
        const float inv = 1.f / se;
        #pragma unroll
        for (int j = 0; j < 4; ++j) {
            const int a = a0 + 8 * j;
            if (a < AA) out[(size_t)(row0 + r) * AA + a] = mix[j] * inv;
        }
    }
}

extern "C" void kernel_launch(void* const* d_in, const int* in_sizes, int n_in,
                              void* d_out, int out_size, void* d_ws, size_t ws_size,
                              hipStream_t stream) {
    const float* state   = (const float*)d_in[0];
    const float* fitness = (const float*)d_in[1];
    const float* proto   = (const float*)d_in[2];
    const float* enc_W1  = (const float*)d_in[3];
    const float* enc_b1  = (const float*)d_in[4];
    const float* ln_g    = (const float*)d_in[5];
    const float* ln_b    = (const float*)d_in[6];
    const float* enc_W2  = (const float*)d_in[7];
    const float* enc_b2  = (const float*)d_in[8];
    const float* dec_W1  = (const float*)d_in[9];
    const float* dec_b1  = (const float*)d_in[10];
    const float* dec_W2  = (const float*)d_in[11];
    const float* dec_b2  = (const float*)d_in[12];
    const float* tc_W    = (const float*)d_in[13];
    const float* tc_b    = (const float*)d_in[14];
    const float* tc_cW   = (const float*)d_in[15];
    const float* tc_cb   = (const float*)d_in[16];
    const float* w_prev  = (const float*)d_in[19];
    float* out = (float*)d_out;

    // workspace layout (bytes)
    short* W1T    = (short*)d_ws;                       // 256*320*2 = 163840
    short* W3T    = (short*)((char*)d_ws + 163840);     // 128*256*2 = 65536
    short* protoB = (short*)((char*)d_ws + 229376);     // 16*256*2  = 8192
    float* cmn    = (float*)((char*)d_ws + 237568);     // 128*4
    float* conc   = (float*)((char*)d_ws + 238080);     // 480*4

    pre_kernel<<<161, 256, 0, stream>>>(proto, enc_W2, enc_b2, enc_W1,
                                        dec_W1, dec_b1, dec_W2, dec_b2,
                                        W1T, W3T, protoB, cmn, conc);
    main_kernel<<<NBATCH / ROWS, 256, 0, stream>>>(state, fitness,
                                                   enc_b1, ln_g, ln_b,
                                                   tc_W, tc_b, tc_cW, tc_cb, w_prev,
                                                   W1T, W3T, protoB, cmn, conc, out);
}

// Round 4
// 133.617 us; speedup vs baseline: 2.1046x; 1.1601x over previous
//
#include <hip/hip_runtime.h>

typedef __attribute__((ext_vector_type(8))) short bf16x8;
typedef __attribute__((ext_vector_type(4))) float f32x4;

#define NBATCH 16384
#define SS     300
#define AA     30
#define ROWS   16
#define SSTR   352     // shorts per state row in LDS
#define HSTR   280     // shorts per h/danger row in LDS
#define LSTR   132     // floats per logits row in LDS
#define K1P    320
#define SCALEF 0.0625f
#define ETA0   0.1f

__device__ __forceinline__ short f2b(float x) {
    unsigned u = __float_as_uint(x);
    unsigned r = (u + 0x7FFFu + ((u >> 16) & 1u)) >> 16;
    return (short)r;
}
__device__ __forceinline__ float b2f(short s) {
    return __uint_as_float(((unsigned)(unsigned short)s) << 16);
}
__device__ __forceinline__ float tanh_fast(float x) {
    float e = __expf(2.f * x);
    return 1.f - 2.f / (e + 1.f);
}

// ---------------------------------------------------------------------------
// Pre-kernel, 61 blocks. All global reads coalesced or tiny.
//  0..31 : W3P  (m=bid>>2, jt=bid&3) via MFMA from LDS-staged W2 tile
//  32..41: W1P  (kt=bid-32) fragment-packed [kt][q][n][8]
//  42    : PDP  proto rows 0..15 + cW as row 16, packed [kt][q][n'][8]
//  43    : TCP  tcW packed [q][n][8] (K padded 12->32)
//  44    : cmn
//  45..60: conc (one m per block)
// ---------------------------------------------------------------------------
__global__ __launch_bounds__(256) void pre_kernel(
    const float* __restrict__ proto, const float* __restrict__ W1,
    const float* __restrict__ W2,   const float* __restrict__ b2,
    const float* __restrict__ tcW,  const float* __restrict__ cW,
    const float* __restrict__ dW1,  const float* __restrict__ db1,
    const float* __restrict__ dW2,  const float* __restrict__ db2,
    short* __restrict__ W1P, short* __restrict__ W3P,
    short* __restrict__ PDP, short* __restrict__ TCP,
    float* __restrict__ cmn, float* __restrict__ conc)
{
    __shared__ short sbuf[64 * 264 + 4096];   // 41984 B, reused per branch
    const int t = threadIdx.x;
    const int bid = blockIdx.x;

    if (bid < 32) {
        // ---- W3P: W3[c][j] = sum_e W2[j][m*256+e] * proto[n][e] ----
        const int m = bid >> 2, jt = bid & 3;
        short* W2s = sbuf;                  // [64][264] bf16
        short* prS = sbuf + 64 * 264;       // packed proto B-frags, 4096 shorts
        #pragma unroll 4
        for (int it = 0; it < 64; ++it) {
            const int idx = it * 256 + t, j = idx >> 8, e = idx & 255;
            W2s[j * 264 + e] = f2b(W2[(size_t)(jt * 64 + j) * 2048 + m * 256 + e]);
        }
        for (int it = 0; it < 16; ++it) {
            const int id = it * 256 + t, chunk = id >> 3, j8 = id & 7;
            const int kt = chunk >> 6, rem = chunk & 63, q = rem >> 4, n = rem & 15;
            prS[id] = f2b(proto[n * 256 + kt * 32 + q * 8 + j8]);
        }
        __syncthreads();
        const int lane = t & 63, wv = t >> 6, l15 = lane & 15, q = lane >> 4;
        f32x4 acc = {0.f, 0.f, 0.f, 0.f};
        for (int kt = 0; kt < 8; ++kt) {
            bf16x8 a = *(const bf16x8*)&W2s[(wv * 16 + l15) * 264 + kt * 32 + q * 8];
            bf16x8 b = *(const bf16x8*)&prS[((kt * 4 + q) * 16 + l15) * 8];
            acc = __builtin_amdgcn_mfma_f32_16x16x32_bf16(a, b, acc, 0, 0, 0);
        }
        #pragma unroll
        for (int reg = 0; reg < 4; ++reg) {
            const int jg = jt * 64 + wv * 16 + q * 4 + reg;
            const int c = m * 16 + l15;
            const int ktj = jg >> 5, qj = (jg >> 3) & 3, j8 = jg & 7;
            W3P[((ktj * 4 + qj) * 128 + c) * 8 + j8] = f2b(acc[reg]);
        }
    } else if (bid < 42) {
        // ---- W1P ----
        const int kt = bid - 32;
        short* W1s = sbuf;                  // [32][256]
        #pragma unroll 4
        for (int it = 0; it < 32; ++it) {
            const int idx = it * 256 + t, k = idx >> 8, n = idx & 255;
            const int kg = kt * 32 + k;
            W1s[k * 256 + n] = (kg < SS) ? f2b(W1[(size_t)kg * 256 + n]) : (short)0;
        }
        __syncthreads();
        for (int it = 0; it < 4; ++it) {
            const int id = it * 256 + t, q = id >> 8, n = id & 255;
            bf16x8 v;
            #pragma unroll
            for (int j = 0; j < 8; ++j) v[j] = W1s[(q * 8 + j) * 256 + n];
            *(bf16x8*)&W1P[((kt * 4 + q) * 256 + n) * 8] = v;
        }
    } else if (bid == 42) {
        for (int it = 0; it < 32; ++it) {
            const int id = it * 256 + t, chunk = id >> 3, j8 = id & 7;
            const int kt = chunk >> 7, q = (chunk >> 5) & 3, np = chunk & 31;
            const int k = kt * 32 + q * 8 + j8;
            float v = 0.f;
            if (np < 16) v = proto[np * 256 + k];
            else if (np == 16) v = cW[k];
            PDP[id] = f2b(v);
        }
    } else if (bid == 43) {
        for (int it = 0; it < 32; ++it) {
            const int id = it * 256 + t, chunk = id >> 3, j8 = id & 7;
            const int q = chunk >> 8, n = chunk & 255, k = q * 8 + j8;
            TCP[id] = (k < 12) ? f2b(tcW[k * 256 + n]) : (short)0;
        }
    } else if (bid == 44) {
        float* b2s = (float*)sbuf;          // 2048
        float* prF = (float*)sbuf + 2048;   // 4096
        for (int it = 0; it < 8; ++it)  b2s[it * 256 + t] = b2[it * 256 + t];
        for (int it = 0; it < 16; ++it) prF[it * 256 + t] = proto[it * 256 + t];
        __syncthreads();
        if (t < 128) {
            const int mq = t >> 4, n = t & 15;
            float acc = 0.f;
            for (int e = 0; e < 256; ++e) acc += b2s[mq * 256 + e] * prF[n * 256 + e];
            cmn[t] = acc;
        }
    } else {
        const int m = bid - 45;
        float* hd = (float*)sbuf;
        if (t < 128) {
            float acc = db1[m * 128 + t];
            const float* wp = dW1 + (size_t)m * 256 * 128 + t;
            const float* p = proto + m * 256;
            for (int e = 0; e < 256; ++e) acc += p[e] * wp[e * 128];
            hd[t] = fmaxf(acc, 0.f);
        }
        __syncthreads();
        if (t < AA) {
            float acc = db2[m * AA + t];
            const float* wp = dW2 + (size_t)m * 128 * AA + t;
            for (int h = 0; h < 128; ++h) acc += hd[h] * wp[h * AA];
            conc[m * AA + t] = fmaxf(acc, 0.f) + log1pf(__expf(-fabsf(acc)));
        }
    }
}

// ---------------------------------------------------------------------------
// Main kernel: 16 rows/block, 1024 blocks, 256 threads (4 waves), ~25 KB LDS.
// ---------------------------------------------------------------------------
__global__ __launch_bounds__(256, 5) void main_kernel(
    const float* __restrict__ state, const float* __restrict__ fitness,
    const float* __restrict__ b1,
    const float* __restrict__ lng,  const float* __restrict__ lnb,
    const float* __restrict__ tcb,  const float* __restrict__ cb,
    const float* __restrict__ pw,
    const short* __restrict__ W1P,  const short* __restrict__ W3P,
    const short* __restrict__ PDP,  const short* __restrict__ TCP,
    const float* __restrict__ cmn,  const float* __restrict__ conc,
    float* __restrict__ out)
{
    const int t    = threadIdx.x;
    const int row0 = blockIdx.x * ROWS;
    const int w    = t >> 6;
    const int lane = t & 63;
    const int l15  = lane & 15;
    const int q    = lane >> 4;

    __shared__ short sA[ROWS * SSTR];      // state -> h (stride HSTR); tail: wrep
    __shared__ short sB[ROWS * HSTR];      // danger -> logits fp32
    __shared__ short s_mfB[ROWS * 32];
    __shared__ float s_red[ROWS][8];
    __shared__ float s_mu[ROWS], s_rstd[ROWS];
    __shared__ float s_dd[ROWS * 16];      // ddot -> w_ot -> w
    __shared__ float s_crisis[ROWS];
    __shared__ float s_cmn[128];
    __shared__ float s_conc[16 * AA];

    float* s_log  = (float*)sB;                  // [ROWS][LSTR]
    float* s_wrep = (float*)&sA[ROWS * HSTR];    // 16*16 fp32 in sA tail

    // ---- P1: stage state bf16 (K padded to 320) + small tables ----
    #pragma unroll 4
    for (int it = 0; it < 20; ++it) {
        const int idx = it * 256 + t, r = idx / K1P, k = idx - r * K1P;
        sA[r * SSTR + k] = (k < SS) ? f2b(state[(size_t)(row0 + r) * SS + k]) : (short)0;
    }
    for (int it = t; it < 128 + 16 * AA; it += 256) {
        if (it < 128) s_cmn[it] = cmn[it];
        else s_conc[it - 128] = conc[it - 128];
    }
    __syncthreads();

    // ---- P2: market features -> s_mfB bf16 (16 lanes per row) ----
    {
        const int r = t >> 4, g = t & 15;
        float sp = 0.f, sp2 = 0.f, sps = 0.f;
        if (g < 15) {
            #pragma unroll
            for (int jj = 0; jj < 2; ++jj) {
                const int i = 2 * g + jj;
                const float p = b2f(sA[r * SSTR + 1 + i]);
                const float s = b2f(sA[r * SSTR + 31 + i]);
                sp += p; sp2 += p * p; sps += p * s;
            }
        }
        #pragma unroll
        for (int off = 1; off < 16; off <<= 1) {
            sp  += __shfl_xor(sp, off);
            sp2 += __shfl_xor(sp2, off);
            sps += __shfl_xor(sps, off);
        }
        if (g < 8) s_mfB[r * 32 + 4 + g] = sA[r * SSTR + 61 + 30 * g];
        for (int k = 12 + g; k < 32; k += 16) s_mfB[r * 32 + k] = 0;
        if (g == 0) {
            const float bal = b2f(sA[r * SSTR]);
            const float pm = sp * (1.f / 30.f);
            const float var = (sp2 - 30.f * pm * pm) * (1.f / 29.f);
            const float pstd = sqrtf(fmaxf(var, 0.f)) + 1e-8f;
            s_mfB[r * 32 + 0] = sA[r * SSTR];
            s_mfB[r * 32 + 1] = f2b(pm);
            s_mfB[r * 32 + 2] = f2b(pstd);
            s_mfB[r * 32 + 3] = f2b(bal / (bal + sps + 1e-8f));
        }
    }
    __syncthreads();

    // ---- P3: danger = tanh(mf @ tcW + tcb) via one MFMA k-tile ----
    {
        f32x4 dacc[4];
        #pragma unroll
        for (int u = 0; u < 4; ++u) dacc[u] = (f32x4){0.f, 0.f, 0.f, 0.f};
        bf16x8 a = *(const bf16x8*)&s_mfB[l15 * 32 + q * 8];
        #pragma unroll
        for (int u = 0; u < 4; ++u) {
            bf16x8 b = *(const bf16x8*)&TCP[((q << 8) | (w * 64 + u * 16 + l15)) * 8];
            dacc[u] = __builtin_amdgcn_mfma_f32_16x16x32_bf16(a, b, dacc[u], 0, 0, 0);
        }
        #pragma unroll
        for (int u = 0; u < 4; ++u) {
            const int col = w * 64 + u * 16 + l15;
            const float tb = tcb[col];
            #pragma unroll
            for (int reg = 0; reg < 4; ++reg)
                sB[(q * 4 + reg) * HSTR + col] = f2b(tanh_fast(dacc[u][reg] + tb));
        }
    }
    __syncthreads();

    // ---- P4: wave0 ddot (proto), wave1 crisis (cW row) — both MFMA ----
    if (w == 0) {
        f32x4 acc = {0.f, 0.f, 0.f, 0.f};
        for (int kt = 0; kt < 8; ++kt) {
            bf16x8 a = *(const bf16x8*)&sB[l15 * HSTR + kt * 32 + q * 8];
            bf16x8 b = *(const bf16x8*)&PDP[((kt * 4 + q) * 32 + l15) * 8];
            acc = __builtin_amdgcn_mfma_f32_16x16x32_bf16(a, b, acc, 0, 0, 0);
        }
        #pragma unroll
        for (int reg = 0; reg < 4; ++reg)
            s_dd[(q * 4 + reg) * 16 + l15] = acc[reg];
    } else if (w == 1) {
        f32x4 acc = {0.f, 0.f, 0.f, 0.f};
        for (int kt = 0; kt < 8; ++kt) {
            bf16x8 a = *(const bf16x8*)&sB[l15 * HSTR + kt * 32 + q * 8];
            bf16x8 b = *(const bf16x8*)&PDP[((kt * 4 + q) * 32 + 16 + l15) * 8];
            acc = __builtin_amdgcn_mfma_f32_16x16x32_bf16(a, b, acc, 0, 0, 0);
        }
        if (l15 == 0) {
            const float cbv = cb[0];
            #pragma unroll
            for (int reg = 0; reg < 4; ++reg)
                s_crisis[q * 4 + reg] = 1.f / (1.f + __expf(-(acc[reg] + cbv)));
        }
    }

    // ---- P5: GEMM1 h_pre = state @ W1 (B from packed global, coalesced) ----
    f32x4 acc[4];
    #pragma unroll
    for (int u = 0; u < 4; ++u) acc[u] = (f32x4){0.f, 0.f, 0.f, 0.f};
    for (int kt = 0; kt < 10; ++kt) {
        bf16x8 a = *(const bf16x8*)&sA[l15 * SSTR + kt * 32 + q * 8];
        bf16x8 bfr[4];
        #pragma unroll
        for (int u = 0; u < 4; ++u)
            bfr[u] = *(const bf16x8*)&W1P[((kt * 4 + q) * 256 + (w * 64 + u * 16 + l15)) * 8];
        #pragma unroll
        for (int u = 0; u < 4; ++u)
            acc[u] = __builtin_amdgcn_mfma_f32_16x16x32_bf16(a, bfr[u], acc[u], 0, 0, 0);
    }

    // ---- P6: +b1, LN partials via in-quad xor shuffles ----
    {
        float b1v[4];
        #pragma unroll
        for (int u = 0; u < 4; ++u) b1v[u] = b1[w * 64 + u * 16 + l15];
        #pragma unroll
        for (int reg = 0; reg < 4; ++reg) {
            float s = 0.f, s2 = 0.f;
            #pragma unroll
            for (int u = 0; u < 4; ++u) {
                const float v = acc[u][reg] + b1v[u];
                acc[u][reg] = v;
                s += v; s2 += v * v;
            }
            #pragma unroll
            for (int off = 1; off < 16; off <<= 1) {
                s  += __shfl_xor(s, off);
                s2 += __shfl_xor(s2, off);
            }
            if (l15 == 0) {
                const int row = q * 4 + reg;
                s_red[row][w * 2]     = s;
                s_red[row][w * 2 + 1] = s2;
            }
        }
    }
    __syncthreads();
    if (t < ROWS) {
        float S = 0.f, S2 = 0.f;
        #pragma unroll
        for (int ww = 0; ww < 4; ++ww) { S += s_red[t][2 * ww]; S2 += s_red[t][2 * ww + 1]; }
        const float mu = S * (1.f / 256.f);
        const float var = S2 * (1.f / 256.f) - mu * mu;
        s_mu[t] = mu; s_rstd[t] = rsqrtf(var + 1e-5f);
    }
    __syncthreads();

    // ---- P7: LN + relu -> h bf16 in sA (stride HSTR) ----
    {
        float gv[4], bv[4];
        #pragma unroll
        for (int u = 0; u < 4; ++u) {
            gv[u] = lng[w * 64 + u * 16 + l15];
            bv[u] = lnb[w * 64 + u * 16 + l15];
        }
        #pragma unroll
        for (int reg = 0; reg < 4; ++reg) {
            const int row = q * 4 + reg;
            const float mu = s_mu[row], rs = s_rstd[row];
            #pragma unroll
            for (int u = 0; u < 4; ++u) {
                const int col = w * 64 + u * 16 + l15;
                const float v = fmaxf((acc[u][reg] - mu) * rs * gv[u] + bv[u], 0.f);
                sA[row * HSTR + col] = f2b(v);
            }
        }
    }
    __syncthreads();

    // ---- P8: GEMM2' logits = SCALE*(h @ W3 + cmn + ddot) ----
    {
        f32x4 c2[2];
        c2[0] = (f32x4){0.f, 0.f, 0.f, 0.f};
        c2[1] = (f32x4){0.f, 0.f, 0.f, 0.f};
        for (int kt = 0; kt < 8; ++kt) {
            bf16x8 a = *(const bf16x8*)&sA[l15 * HSTR + kt * 32 + q * 8];
            bf16x8 b0 = *(const bf16x8*)&W3P[((kt * 4 + q) * 128 + w * 32 + l15) * 8];
            bf16x8 b1f = *(const bf16x8*)&W3P[((kt * 4 + q) * 128 + w * 32 + 16 + l15) * 8];
            c2[0] = __builtin_amdgcn_mfma_f32_16x16x32_bf16(a, b0, c2[0], 0, 0, 0);
            c2[1] = __builtin_amdgcn_mfma_f32_16x16x32_bf16(a, b1f, c2[1], 0, 0, 0);
        }
        const float cm0 = s_cmn[w * 32 + l15], cm1 = s_cmn[w * 32 + 16 + l15];
        #pragma unroll
        for (int reg = 0; reg < 4; ++reg) {
            const int row = q * 4 + reg;
            const float dd = s_dd[row * 16 + l15];
            s_log[row * LSTR + w * 32 + l15]      = SCALEF * (c2[0][reg] + cm0 + dd);
            s_log[row * LSTR + w * 32 + 16 + l15] = SCALEF * (c2[1][reg] + cm1 + dd);
        }
    }
    __syncthreads();

    // ---- P9: softmax over n per (r,m) ----
    if (t < 128) {
        const int r = t >> 3, m = t & 7;
        float* lg = &s_log[r * LSTR + m * 16];
        float mx = lg[0];
        #pragma unroll
        for (int n = 1; n < 16; ++n) mx = fmaxf(mx, lg[n]);
        float sum = 0.f, p[16];
        #pragma unroll
        for (int n = 0; n < 16; ++n) { p[n] = __expf(lg[n] - mx); sum += p[n]; }
        const float inv = 1.f / sum;
        #pragma unroll
        for (int n = 0; n < 16; ++n) lg[n] = p[n] * inv;
    }
    __syncthreads();

    // ---- P10: w_ot (into s_dd) + unnormalized w_rep ----
    {
        const int r = t >> 4, n = t & 15;
        float wot = 0.f;
        #pragma unroll
        for (int m = 0; m < 8; ++m) wot += s_log[r * LSTR + m * 16 + n];
        s_dd[t] = wot * 0.125f;
        s_wrep[t] = pw[n] * __expf(ETA0 * fitness[(size_t)(row0 + r) * 16 + n]);
    }
    __syncthreads();

    // ---- P11: blend -> w (in s_dd) ----
    if (t < ROWS) {
        float srep = 0.f;
        #pragma unroll
        for (int n = 0; n < 16; ++n) srep += s_wrep[t * 16 + n];
        const float irep = 1.f / (srep + 1e-8f);
        const float alpha = 0.06f + 0.24f * (1.f - s_crisis[t]);
        float wn[16], sw = 0.f;
        #pragma unroll
        for (int n = 0; n < 16; ++n) {
            wn[n] = alpha * s_dd[t * 16 + n] + (1.f - alpha) * s_wrep[t * 16 + n] * irep;
            sw += wn[n];
        }
        const float isw = 1.f / (sw + 1e-8f);
        #pragma unroll
        for (int n = 0; n < 16; ++n) s_dd[t * 16 + n] = wn[n] * isw;
    }
    __syncthreads();

    // ---- P12: mixed = w@conc + 1, softmax(30), write ----
    {
        const int r = w * 4 + q;
        const int a0 = l15;
        const int a1 = a0 + 16;
        const bool v1 = a1 < AA;
        float wreg[16];
        #pragma unroll
        for (int n = 0; n < 16; ++n) wreg[n] = s_dd[r * 16 + n];
        float m0 = 1.f, m1 = 1.f;
        const int a1s = v1 ? a1 : 0;
        #pragma unroll
        for (int n = 0; n < 16; ++n) {
            m0 = fmaf(wreg[n], s_conc[n * AA + a0], m0);
            m1 = fmaf(wreg[n], s_conc[n * AA + a1s], m1);
        }
        float mx = v1 ? fmaxf(m0, m1) : m0;
        #pragma unroll
        for (int off = 1; off < 16; off <<= 1) mx = fmaxf(mx, __shfl_xor(mx, off));
        float e0 = __expf(m0 - mx);
        float e1 = v1 ? __expf(m1 - mx) : 0.f;
        float se = e0 + e1;
        #pragma unroll
        for (int off = 1; off < 16; off <<= 1) se += __shfl_xor(se, off);
        const float inv = 1.f / se;
        out[(size_t)(row0 + r) * AA + a0] = e0 * inv;
        if (v1) out[(size_t)(row0 + r) * AA + a1] = e1 * inv;
    }
}

extern "C" void kernel_launch(void* const* d_in, const int* in_sizes, int n_in,
                              void* d_out, int out_size, void* d_ws, size_t ws_size,
                              hipStream_t stream) {
    const float* state   = (const float*)d_in[0];
    const float* fitness = (const float*)d_in[1];
    const float* proto   = (const float*)d_in[2];
    const float* enc_W1  = (const float*)d_in[3];
    const float* enc_b1  = (const float*)d_in[4];
    const float* ln_g    = (const float*)d_in[5];
    const float* ln_b    = (const float*)d_in[6];
    const float* enc_W2  = (const float*)d_in[7];
    const float* enc_b2  = (const float*)d_in[8];
    const float* dec_W1  = (const float*)d_in[9];
    const float* dec_b1  = (const float*)d_in[10];
    const float* dec_W2  = (const float*)d_in[11];
    const float* dec_b2  = (const float*)d_in[12];
    const float* tc_W    = (const float*)d_in[13];
    const float* tc_b    = (const float*)d_in[14];
    const float* tc_cW   = (const float*)d_in[15];
    const float* tc_cb   = (const float*)d_in[16];
    const float* w_prev  = (const float*)d_in[19];
    float* out = (float*)d_out;

    short* W1P = (short*)d_ws;              // 10*4*256*8 = 81920 shorts
    short* W3P = W1P + 81920;               // 8*4*128*8  = 32768
    short* PDP = W3P + 32768;               // 8*4*32*8   = 8192
    short* TCP = PDP + 8192;                // 4*256*8    = 8192
    float* cmn  = (float*)(TCP + 8192);     // 128
    float* conc = cmn + 128;                // 480

    pre_kernel<<<61, 256, 0, stream>>>(proto, enc_W1, enc_W2, enc_b2,
                                       tc_W, tc_cW,
                                       dec_W1, dec_b1, dec_W2, dec_b2,
                                       W1P, W3P, PDP, TCP, cmn, conc);
    main_kernel<<<NBATCH / ROWS, 256, 0, stream>>>(state, fitness,
                                                   enc_b1, ln_g, ln_b,
                                                   tc_b, tc_cb, w_prev,
                                                   W1P, W3P, PDP, TCP, cmn, conc, out);
}